// Round 5
// baseline (289.906 us; speedup 1.0000x reference)
//
#include <hip/hip_runtime.h>

// ---------------------------------------------------------------------------
// ElementwiseTensorProducts — wave-autonomous bf16-MFMA kernel, ZERO barriers.
// Grid 4096 x 64 threads (1 wave). Each wave owns 16 tokens end-to-end:
//   1) A-frags (z0 16x128, z1 48x128) loaded DIRECTLY from global, fp32->bf16
//   2) proj MFMAs: full rank 64 per wave -> all 8 proj matrices share the
//      SAME C-layout -> tensor products are pure register math (no LDS!)
//   3) P0/P1 written to LDS once (b32-packed via k-interleaved weight layout)
//      = the only C->A layout transpose needed
//   4) output GEMMs (k-interleaved W0o'/W1o' frags from d_ws) + store
// Weights are pre-baked into MFMA fragments by etp_setup (149 KB workspace).
// ---------------------------------------------------------------------------

typedef float  f32x4  __attribute__((ext_vector_type(4)));
typedef __bf16 bf16x8 __attribute__((ext_vector_type(8)));

#define LDS_BYTES 22528
#define P1_BASE   4096
#define P1_STRIDE 6144

// fragment catalog in d_ws: wsf[fid*64 + lane], 16 B each
// FA: proj weights   (mat:4)(n:4)(k:4)        ids [0,64)
// FB0: W0o' (k-interleaved p00/p110)  (n8:8)(k:4)   ids [64,96)
// FB1: W1o' (k-interleaved q011/q101 | q111) (n8:8)(k6:6) ids [96,144)
#define FA_ID(mat,n,k) (((mat)*4+(n))*4+(k))
#define FB0_ID(n8,k)   (64 + (n8)*4 + (k))
#define FB1_ID(n8,k6)  (96 + (n8)*6 + (k6))
#define NFRAG 144
#define WS_NEED (NFRAG * 64 * 16)

__device__ __forceinline__ unsigned packbf(float lo, float hi) {
    unsigned a = (unsigned)__builtin_bit_cast(unsigned short, (__bf16)lo);
    unsigned b = (unsigned)__builtin_bit_cast(unsigned short, (__bf16)hi);
    return a | (b << 16);
}
__device__ __forceinline__ void st_bf(void* p, float v) {
    *(unsigned short*)p = __builtin_bit_cast(unsigned short, (__bf16)v);
}
__device__ __forceinline__ bf16x8 cvtW(const float* p) {
    float4 a = *(const float4*)p;
    float4 b = *(const float4*)(p + 4);
    bf16x8 r;
    r[0] = (__bf16)a.x; r[1] = (__bf16)a.y; r[2] = (__bf16)a.z; r[3] = (__bf16)a.w;
    r[4] = (__bf16)b.x; r[5] = (__bf16)b.y; r[6] = (__bf16)b.z; r[7] = (__bf16)b.w;
    return r;
}
__device__ __forceinline__ f32x4 mm(bf16x8 a, bf16x8 b, f32x4 c) {
    return __builtin_amdgcn_mfma_f32_16x16x32_bf16(a, b, c, 0, 0, 0);
}

// k-interleave maps (shared by setup and fallback):
// W0o' k-index kk -> original col: even -> kk/2 (p00), odd -> 64+kk/2 (p110)
__device__ __forceinline__ int map_b0(int kk) { return (kk & 1) ? 64 + (kk >> 1) : (kk >> 1); }
// W1o' kk<128: even -> kk/2 (q011), odd -> 64+kk/2 (q101); kk>=128 -> kk (q111)
__device__ __forceinline__ int map_b1(int kk) { return kk >= 128 ? kk : ((kk & 1) ? 64 + (kk >> 1) : (kk >> 1)); }

__device__ __forceinline__ bf16x8 gatherB0(const float* W0o, int n8, int k, int lr, int lg) {
    bf16x8 r; const int c = n8 * 16 + lr;
    #pragma unroll
    for (int e = 0; e < 8; ++e) r[e] = (__bf16)W0o[c * 128 + map_b0(k * 32 + lg * 8 + e)];
    return r;
}
__device__ __forceinline__ bf16x8 gatherB1(const float* W1o, int n8, int k6, int lr, int lg) {
    bf16x8 r; const int c = n8 * 16 + lr;
    #pragma unroll
    for (int e = 0; e < 8; ++e) r[e] = (__bf16)W1o[c * 192 + map_b1(k6 * 32 + lg * 8 + e)];
    return r;
}

// ---------------- setup: fp32 weights -> bf16 fragment buffer ---------------
__global__ void etp_setup(const float* __restrict__ W0l, const float* __restrict__ W0r,
                          const float* __restrict__ W1l, const float* __restrict__ W1r,
                          const float* __restrict__ W0o, const float* __restrict__ W1o,
                          bf16x8* __restrict__ wsf)
{
    const int gid = blockIdx.x * 256 + threadIdx.x;
    if (gid >= NFRAG * 64) return;
    const int fid = gid >> 6, l = gid & 63, lr = l & 15, lg = l >> 4;
    bf16x8 r;
    if (fid < 64) {
        const int mat = fid >> 4, n = (fid >> 2) & 3, k = fid & 3;
        const float* Wm = (mat == 0) ? W0l : (mat == 1) ? W0r : (mat == 2) ? W1l : W1r;
        r = cvtW(Wm + (n * 16 + lr) * 128 + k * 32 + lg * 8);
    } else if (fid < 96) {
        const int f = fid - 64;
        r = gatherB0(W0o, f >> 2, f & 3, lr, lg);
    } else {
        const int f = fid - 96;
        r = gatherB1(W1o, f / 6, f % 6, lr, lg);
    }
    wsf[fid * 64 + l] = r;
}

// ---------------- main kernel ------------------------------------------------
template <bool WS>
__global__ __launch_bounds__(64, 2)
void etp_main(const float* __restrict__ z0, const float* __restrict__ z1,
              const float* __restrict__ W0l, const float* __restrict__ b0l,
              const float* __restrict__ W0r, const float* __restrict__ b0r,
              const float* __restrict__ W1l, const float* __restrict__ W1r,
              const float* __restrict__ W0o, const float* __restrict__ b0o,
              const float* __restrict__ W1o,
              const bf16x8* __restrict__ wsf,
              float* __restrict__ out0, float* __restrict__ out1)
{
    __shared__ __align__(16) unsigned char smem[LDS_BYTES];
    const int l  = threadIdx.x;
    const int lr = l & 15;     // A-row (token) / B n-row / C col
    const int lg = l >> 4;     // k-group; C rows = lg*4+j
    const int m0 = blockIdx.x * 16;

    // ---- A-fragments straight from global (each element read once) --------
    bf16x8 za0[4], za1[3][4];
    #pragma unroll
    for (int k = 0; k < 4; ++k)
        za0[k] = cvtW(z0 + (size_t)(m0 + lr) * 128 + k * 32 + lg * 8);
    #pragma unroll
    for (int i = 0; i < 3; ++i)
        #pragma unroll
        for (int k = 0; k < 4; ++k)
            za1[i][k] = cvtW(z1 + ((size_t)(m0 + lr) * 3 + i) * 128 + k * 32 + lg * 8);

    // ---- projections: full rank per wave -----------------------------------
    f32x4 zero = {0.f, 0.f, 0.f, 0.f};
    f32x4 aL0[4], aR0[4], aL1[3][4], aR1[3][4];
    #pragma unroll
    for (int n = 0; n < 4; ++n) {
        aL0[n] = zero; aR0[n] = zero;
        #pragma unroll
        for (int i = 0; i < 3; ++i) { aL1[i][n] = zero; aR1[i][n] = zero; }
    }
    #pragma unroll
    for (int n = 0; n < 4; ++n) {
        #pragma unroll
        for (int k = 0; k < 4; ++k) {
            bf16x8 w0 = WS ? wsf[FA_ID(0, n, k) * 64 + l]
                           : cvtW(W0l + (n * 16 + lr) * 128 + k * 32 + lg * 8);
            bf16x8 w1 = WS ? wsf[FA_ID(1, n, k) * 64 + l]
                           : cvtW(W0r + (n * 16 + lr) * 128 + k * 32 + lg * 8);
            bf16x8 w2 = WS ? wsf[FA_ID(2, n, k) * 64 + l]
                           : cvtW(W1l + (n * 16 + lr) * 128 + k * 32 + lg * 8);
            bf16x8 w3 = WS ? wsf[FA_ID(3, n, k) * 64 + l]
                           : cvtW(W1r + (n * 16 + lr) * 128 + k * 32 + lg * 8);
            aL0[n] = mm(za0[k], w0, aL0[n]);
            aR0[n] = mm(za0[k], w1, aR0[n]);
            #pragma unroll
            for (int i = 0; i < 3; ++i) {
                aL1[i][n] = mm(za1[i][k], w2, aL1[i][n]);
                aR1[i][n] = mm(za1[i][k], w3, aR1[i][n]);
            }
        }
    }
    // biases on the z0 pair (rank col = n*16+lr)
    #pragma unroll
    for (int n = 0; n < 4; ++n) {
        const float blv = b0l[n * 16 + lr], brv = b0r[n * 16 + lr];
        #pragma unroll
        for (int j = 0; j < 4; ++j) { aL0[n][j] += blv; aR0[n][j] += brv; }
    }

    // ---- tensor products: pure register math; pack + single LDS write ------
    // P0 row t: 128 bf16, byte 2*kk, kk even=p00, odd=p110 (k-interleaved)
    #pragma unroll
    for (int n = 0; n < 4; ++n)
        #pragma unroll
        for (int j = 0; j < 4; ++j) {
            const int row = lg * 4 + j, sw = (row & 7) << 4;
            const float p00  = aL0[n][j] * aR0[n][j];
            const float p110 = aL1[0][n][j] * aR1[0][n][j]
                             + aL1[1][n][j] * aR1[1][n][j]
                             + aL1[2][n][j] * aR1[2][n][j];
            *(unsigned*)(smem + row * 256 + ((4 * (n * 16 + lr)) ^ sw)) = packbf(p00, p110);
        }
    // P1[i] row t: 192 bf16; bytes [0,256) pairs (q011,q101); [256,384) q111
    #pragma unroll
    for (int i = 0; i < 3; ++i) {
        const int i1 = (i == 2) ? 0 : i + 1;
        const int i2 = (i == 0) ? 2 : i - 1;
        unsigned char* base = smem + P1_BASE + i * P1_STRIDE;
        #pragma unroll
        for (int n = 0; n < 4; ++n)
            #pragma unroll
            for (int j = 0; j < 4; ++j) {
                const int row = lg * 4 + j, sw = (row & 7) << 4;
                const float q011 = aL0[n][j] * aR1[i][n][j];
                const float q101 = aL1[i][n][j] * aR0[n][j];
                const float q111 = aL1[i1][n][j] * aR1[i2][n][j]
                                 - aL1[i2][n][j] * aR1[i1][n][j];
                *(unsigned*)(base + row * 384 + ((4 * (n * 16 + lr)) ^ sw)) = packbf(q011, q101);
                st_bf(base + row * 384 + ((256 + 2 * (n * 16 + lr)) ^ sw), q111);
            }
    }

    // ---- output GEMMs (intra-wave LDS: compiler orders via lgkmcnt) --------
    bf16x8 pa0[4], pa1[3][6];
    #pragma unroll
    for (int k = 0; k < 4; ++k)
        pa0[k] = *(const bf16x8*)(smem + lr * 256 + ((k * 64 + lg * 16) ^ ((lr & 7) << 4)));
    #pragma unroll
    for (int i = 0; i < 3; ++i)
        #pragma unroll
        for (int k6 = 0; k6 < 6; ++k6)
            pa1[i][k6] = *(const bf16x8*)(smem + P1_BASE + i * P1_STRIDE + lr * 384 +
                                          ((k6 * 64 + lg * 16) ^ ((lr & 7) << 4)));

    #pragma unroll
    for (int n8 = 0; n8 < 8; ++n8) {
        f32x4 o0 = zero, o1[3] = {zero, zero, zero};
        #pragma unroll
        for (int k = 0; k < 4; ++k) {
            bf16x8 b = WS ? wsf[FB0_ID(n8, k) * 64 + l] : gatherB0(W0o, n8, k, lr, lg);
            o0 = mm(pa0[k], b, o0);
        }
        #pragma unroll
        for (int k6 = 0; k6 < 6; ++k6) {
            bf16x8 b = WS ? wsf[FB1_ID(n8, k6) * 64 + l] : gatherB1(W1o, n8, k6, lr, lg);
            #pragma unroll
            for (int i = 0; i < 3; ++i) o1[i] = mm(pa1[i][k6], b, o1[i]);
        }
        const int c = n8 * 16 + lr;
        const float bo = b0o[c];
        #pragma unroll
        for (int j = 0; j < 4; ++j) {
            const size_t t = m0 + lg * 4 + j;
            out0[t * 128 + c] = o0[j] + bo;
            #pragma unroll
            for (int i = 0; i < 3; ++i)
                out1[(t * 3 + i) * 128 + c] = o1[i][j];
        }
    }
}

extern "C" void kernel_launch(void* const* d_in, const int* in_sizes, int n_in,
                              void* d_out, int out_size, void* d_ws, size_t ws_size,
                              hipStream_t stream)
{
    const float* z0  = (const float*)d_in[0];
    const float* z1  = (const float*)d_in[1];
    const float* W0l = (const float*)d_in[2];
    const float* b0l = (const float*)d_in[3];
    const float* W0r = (const float*)d_in[4];
    const float* b0r = (const float*)d_in[5];
    const float* W1l = (const float*)d_in[6];
    const float* W1r = (const float*)d_in[7];
    const float* W0o = (const float*)d_in[8];
    const float* b0o = (const float*)d_in[9];
    const float* W1o = (const float*)d_in[10];

    const int tokens = in_sizes[0] / 128;        // 65536
    float* out0 = (float*)d_out;
    float* out1 = out0 + (size_t)tokens * 128;
    bf16x8* wsf = (bf16x8*)d_ws;

    if (ws_size >= (size_t)WS_NEED) {
        hipLaunchKernelGGL(etp_setup, dim3((NFRAG * 64 + 255) / 256), dim3(256), 0, stream,
                           W0l, W0r, W1l, W1r, W0o, W1o, wsf);
        hipLaunchKernelGGL((etp_main<true>), dim3(tokens / 16), dim3(64), 0, stream,
                           z0, z1, W0l, b0l, W0r, b0r, W1l, W1r, W0o, b0o, W1o,
                           wsf, out0, out1);
    } else {
        hipLaunchKernelGGL((etp_main<false>), dim3(tokens / 16), dim3(64), 0, stream,
                           z0, z1, W0l, b0l, W0r, b0r, W1l, W1r, W0o, b0o, W1o,
                           wsf, out0, out1);
    }
}